// Round 11
// baseline (3026.068 us; speedup 1.0000x reference)
//
#include <hip/hip_runtime.h>
#include <hip/hip_cooperative_groups.h>
#include <math.h>

namespace cg = cooperative_groups;

#define BB 32
#define NN 1000
#define CC 128
#define FF 128
#define OO 64
#define CAP 128
#define NB 40

// exact replica of JAX's np.float32(1.0 - 0.8) = 0.20000000298023224f
#define RMC ((float)(1.0 - 0.8))

// ======== R21: COOPERATIVE MONO-KERNEL (boundaries -> grid.sync) ========
// Ledger: every within-kernel lever is null (R1 sync, R4 locality, R5 fusion,
// R7 TLP, R9/R10 prefetch - vmcnt FIFO makes fire-and-forget impossible).
// Residual ~120us = 11 dispatch boundaries. R2/R6 failed boundary-cutting by
// STARVING kernels (32-block fusions). This round: ONE cooperative dispatch,
// grid = 800 x 256 (exact R5 shapes), 10 grid.sync()s replace 10 boundaries.
// Every phase body is R5-verbatim; work->block mapping G-strided for
// co-residency safety. k_csr stays separate (streams A at HBM floor).

// ---- CSR build + stage-1 D/dg + fused pre-work (blocks with i==NN) ----
__global__ void k_csr(const float* __restrict__ A, const float* __restrict__ mask,
                      const int* __restrict__ Nn,
                      const float* __restrict__ p0, const float* __restrict__ p1,
                      const float* __restrict__ W0, const float* __restrict__ W1,
                      const float* __restrict__ W2,
                      short* __restrict__ idx, int* __restrict__ cnt,
                      float* __restrict__ D, float* __restrict__ dg,
                      float* __restrict__ m, float* __restrict__ gate,
                      int* __restrict__ ncur0, float* __restrict__ pn,
                      float* __restrict__ Wt){
  int blk = blockIdx.x, lane = threadIdx.x;   // grid 32032, block = 64 (one wave)
  int r8 = blk & 7, t = blk >> 3;             // t 0..4003
  int b = r8 + 8*(t/1001), i = t % 1001;      // XCD-spread decode
  if (i == NN){                            // ---- 32 pre-work blocks ----
    for (int j = lane; j < NN; j += 64){
      float v = mask[b*NN + j]; m[b*NN + j] = v; gate[b*NN + j] = v;
    }
    if (lane == 0) ncur0[b] = Nn[b];
    if (b == 0 && lane == 1){ float s=0.f; for(int c=0;c<FF;c++) s += p0[c]*p0[c]; pn[0] = sqrtf(s); }
    if (b == 1 && lane == 1){ float s=0.f; for(int c=0;c<FF;c++) s += p1[c]*p1[c]; pn[1] = sqrtf(s); }
    // Wt[s][c][f] = W[s][f][c]; 3*FF*CC = 49152 elems, 1536 per block
    for (int e = b*1536 + lane; e < (b+1)*1536; e += 64){
      int s = e / (FF*CC), rem = e % (FF*CC);
      int c = rem >> 7, f = rem & 127;
      const float* W = (s == 0) ? W0 : (s == 1) ? W1 : W2;
      Wt[(size_t)s*FF*CC + rem] = W[f*CC + c];
    }
    return;
  }
  if (mask[b*NN + i] == 0.f){              // A row is all-zero (A pre-masked)
    if (lane == 0){
      cnt[b*NN + i] = 0;
      D[b*NN + i]  = 1.0f / sqrtf(1.0f + 1e-5f);
      dg[b*NN + i] = 0.f;
    }
    return;
  }
  const float4* row = (const float4*)(A + ((size_t)b*NN + i)*NN);
  short* out = idx + ((size_t)b*NN + i)*CAP;
  int count = 0;
  for (int base = 0; base < 250; base += 64){               // 1000 = 250 float4
    int q = base + lane;
    float4 v;
    if (q < 250) v = row[q]; else { v.x=v.y=v.z=v.w=0.f; }
    int lc = (v.x!=0.f) + (v.y!=0.f) + (v.z!=0.f) + (v.w!=0.f);
    int pre = lc;
    #pragma unroll
    for (int off = 1; off < 64; off <<= 1){
      int t2 = __shfl_up(pre, off);
      if (lane >= off) pre += t2;
    }
    int tot = __shfl(pre, 63);
    pre -= lc;                                              // exclusive prefix
    int slot = count + pre;
    int j = q*4;
    if (v.x!=0.f && slot < CAP) out[slot++] = (short)j;
    if (v.y!=0.f && slot < CAP) out[slot++] = (short)(j+1);
    if (v.z!=0.f && slot < CAP) out[slot++] = (short)(j+2);
    if (v.w!=0.f && slot < CAP) out[slot++] = (short)(j+3);
    count += tot;
  }
  if (lane == 0){
    int cn = (count < CAP) ? count : CAP;
    cnt[b*NN + i] = cn;
    float Dv = 1.0f / sqrtf((float)cn + 1.0f + 1e-5f);
    D[b*NN + i]  = Dv;
    dg[b*NN + i] = Dv;                   // mask_i == 1 here
  }
}

// ---- MONO: 3x(agglin [,score,pool,deg]) + fmax + fc in ONE dispatch ----
// grid = G x 256 (G from occupancy, <=800); phases G-strided over their
// natural block counts; all bodies R5-verbatim => bit-exact.
__global__ void k_mono(const float* __restrict__ x, float* __restrict__ H,
                       float* __restrict__ H2,
                       const short* __restrict__ idx, const int* __restrict__ cnt,
                       float* __restrict__ D, float* __restrict__ dg,
                       float* __restrict__ m, float* __restrict__ gate,
                       const float* __restrict__ Wt,
                       const float* __restrict__ b0v, const float* __restrict__ b1v,
                       const float* __restrict__ b2v,
                       const float* __restrict__ p0, const float* __restrict__ p1,
                       const float* __restrict__ pn, int* __restrict__ ncur,
                       float* __restrict__ ysc, float* __restrict__ part,
                       const float* __restrict__ Wfc, const float* __restrict__ bfc,
                       float* __restrict__ out, int G){
  cg::grid_group grid = cg::this_grid();
  __shared__ __align__(16) float t[NB][CC];   // 20.5 KB; aliased by pool/deg/fc
  __shared__ int   nb[4][CAP];                // 2 KB per-wave gather scratch
  __shared__ float dn[4][CAP];                // 2 KB
  int blk = blockIdx.x, tid = threadIdx.x;    // block = 256 = 4 waves
  int w = tid >> 6, lane = tid & 63;
  int g = lane >> 5, l32 = lane & 31;

  for (int s = 0; s < 3; s++){
    const float* hsrc = (s==0) ? x : (s==1) ? H : H2;
    float*       hdst = (s==1) ? H2 : H;
    const float* bias = (s==0) ? b0v : (s==1) ? b1v : b2v;
    const float* Wts  = Wt + (size_t)s*FF*CC;
    // ============ agglin tiles (natural grid 800) ============
    for (int tl = blk; tl < 800; tl += G){
      int r8 = tl & 7, tq = tl >> 3;
      int b = r8 + 8*(tq/25);
      int i0 = (tq % 25) * NB;
      const float* hb = hsrc + (size_t)b*NN*CC;
      int*   nbw = nb[w];
      float* dnw = dn[w];
      // ---- phase 1: aggregate 40 rows into t (R5 body, 10 rows/wave) ----
      for (int q = 0; q < 10; q++){        // wave w owns rows w, w+4, ... w+36
        int lr = q*4 + w;
        int i  = i0 + lr;
        if (m[b*NN + i] == 0.f){           // masked target: T row is zero
          if (g == 0){ float4 z = {0.f,0.f,0.f,0.f}; *(float4*)&t[lr][l32<<2] = z; }
          continue;                        // wave-uniform
        }
        int n = cnt[b*NN + i];
        const short* r = idx + ((size_t)b*NN + i)*CAP;
        int j0 = 0; float d0 = 0.f; bool k0 = false;
        if (lane < n){ j0 = (int)r[lane]; d0 = dg[b*NN + j0]; k0 = (d0 != 0.f); }
        unsigned long long bal = __ballot(k0);
        int pre = __popcll(bal & ((1ull << lane) - 1ull));
        if (k0){ nbw[pre] = j0*CC; dnw[pre] = d0; }
        int nlive = __popcll(bal);
        if (n > 64){                       // wave-uniform branch
          int e = lane + 64; int j1 = 0; float d1 = 0.f; bool k1 = false;
          if (e < n){ j1 = (int)r[e]; d1 = dg[b*NN + j1]; k1 = (d1 != 0.f); }
          unsigned long long bal1 = __ballot(k1);
          int pre1 = __popcll(bal1 & ((1ull << lane) - 1ull));
          if (k1){ nbw[nlive + pre1] = j1*CC; dnw[nlive + pre1] = d1; }
          nlive += __popcll(bal1);
        }
        int np = (nlive + 15) & ~15;       // pad to 16 (CAP=128 safe)
        if (lane < np - nlive){ nbw[nlive + lane] = 0; dnw[nlive + lane] = 0.f; }
        __builtin_amdgcn_wave_barrier();   // fence: LDS writes before reads
        float4 a0 = {0.f,0.f,0.f,0.f}, a1 = a0, a2 = a0, a3 = a0;
        for (int k = 0; k < np; k += 16){
          int e = k + g;
          float4 v0 = *(const float4*)(hb + nbw[e   ] + (l32<<2));
          float4 v1 = *(const float4*)(hb + nbw[e+ 2] + (l32<<2));
          float4 v2 = *(const float4*)(hb + nbw[e+ 4] + (l32<<2));
          float4 v3 = *(const float4*)(hb + nbw[e+ 6] + (l32<<2));
          float4 v4 = *(const float4*)(hb + nbw[e+ 8] + (l32<<2));
          float4 v5 = *(const float4*)(hb + nbw[e+10] + (l32<<2));
          float4 v6 = *(const float4*)(hb + nbw[e+12] + (l32<<2));
          float4 v7 = *(const float4*)(hb + nbw[e+14] + (l32<<2));
          float e0 = dnw[e], e1 = dnw[e+2], e2 = dnw[e+4], e3 = dnw[e+6];
          float e4 = dnw[e+8], e5 = dnw[e+10], e6 = dnw[e+12], e7 = dnw[e+14];
          a0.x += e0*v0.x; a0.y += e0*v0.y; a0.z += e0*v0.z; a0.w += e0*v0.w;
          a1.x += e1*v1.x; a1.y += e1*v1.y; a1.z += e1*v1.z; a1.w += e1*v1.w;
          a2.x += e2*v2.x; a2.y += e2*v2.y; a2.z += e2*v2.z; a2.w += e2*v2.w;
          a3.x += e3*v3.x; a3.y += e3*v3.y; a3.z += e3*v3.z; a3.w += e3*v3.w;
          a0.x += e4*v4.x; a0.y += e4*v4.y; a0.z += e4*v4.z; a0.w += e4*v4.w;
          a1.x += e5*v5.x; a1.y += e5*v5.y; a1.z += e5*v5.z; a1.w += e5*v5.w;
          a2.x += e6*v6.x; a2.y += e6*v6.y; a2.z += e6*v6.z; a2.w += e6*v6.w;
          a3.x += e7*v7.x; a3.y += e7*v7.y; a3.z += e7*v7.z; a3.w += e7*v7.w;
        }
        float4 Y;
        Y.x = (a0.x + a1.x) + (a2.x + a3.x);
        Y.y = (a0.y + a1.y) + (a2.y + a3.y);
        Y.z = (a0.z + a1.z) + (a2.z + a3.z);
        Y.w = (a0.w + a1.w) + (a2.w + a3.w);
        Y.x += __shfl_xor(Y.x, 32);
        Y.y += __shfl_xor(Y.y, 32);
        Y.z += __shfl_xor(Y.z, 32);
        Y.w += __shfl_xor(Y.w, 32);
        float Di = D[b*NN + i];
        float gi = gate[b*NN + i];
        if (g == 0){
          float4 hv = *(const float4*)(hb + (size_t)i*CC + (l32<<2));
          float4 o;
          o.x = Di*Y.x + Di*Di*(gi*hv.x);
          o.y = Di*Y.y + Di*Di*(gi*hv.y);
          o.z = Di*Y.z + Di*Di*(gi*hv.z);
          o.w = Di*Y.w + Di*Di*(gi*hv.w);
          *(float4*)&t[lr][l32<<2] = o;
        }
      }
      __syncthreads();
      // ---- phase 2: FROZEN R3 GEMM body (verbatim) ----
      {
        int fg = tid & 31;                 // 4 consecutive f per thread
        int nr = tid >> 5;                 // 0..7 node-row
        float acc[5][4];
        float4 bi = ((const float4*)bias)[fg];
        #pragma unroll
        for (int n5 = 0; n5 < 5; n5++){
          acc[n5][0]=bi.x; acc[n5][1]=bi.y; acc[n5][2]=bi.z; acc[n5][3]=bi.w;
        }
        for (int c4 = 0; c4 < 32; c4++){
          float4 tv[5];
          #pragma unroll
          for (int n5 = 0; n5 < 5; n5++)
            tv[n5] = *((const float4*)&t[nr + n5*8][c4*4]);
          #pragma unroll
          for (int k = 0; k < 4; k++){
            float4 wv = ((const float4*)Wts)[(size_t)(c4*4 + k)*32 + fg];
            #pragma unroll
            for (int n5 = 0; n5 < 5; n5++){
              float tvv = (k==0) ? tv[n5].x : (k==1) ? tv[n5].y : (k==2) ? tv[n5].z : tv[n5].w;
              acc[n5][0] += tvv*wv.x; acc[n5][1] += tvv*wv.y;
              acc[n5][2] += tvv*wv.z; acc[n5][3] += tvv*wv.w;
            }
          }
        }
        #pragma unroll
        for (int n5 = 0; n5 < 5; n5++){
          int i = i0 + nr + n5*8;
          float mi = m[b*NN + i];
          float4 o4;
          o4.x = fmaxf(acc[n5][0], 0.f)*mi;
          o4.y = fmaxf(acc[n5][1], 0.f)*mi;
          o4.z = fmaxf(acc[n5][2], 0.f)*mi;
          o4.w = fmaxf(acc[n5][3], 0.f)*mi;
          ((float4*)&hdst[((size_t)b*NN + i)*CC])[fg] = o4;
        }
      }
      __syncthreads();                     // protect t before next tile iter
    }
    __threadfence();
    grid.sync();                           // == old agglin->score boundary
    if (s < 2){
      const float* pv = (s==0) ? p0 : p1;
      // ============ score (natural grid 32000 waves) ============
      {
        float pnv = pn[s];
        float pl0 = pv[lane], pl1 = pv[lane + 64];
        int gw = blk*4 + w;
        for (int rr = gw; rr < 32000; rr += G*4){
          int r8b = rr & 7, tt = rr >> 3;
          int b = r8b + 8*(tt/1000), i = tt % 1000;
          const float* hrow = hdst + ((size_t)b*NN + i)*CC;
          float sc = hrow[lane]*pl0 + hrow[lane+64]*pl1;
          for (int off = 32; off > 0; off >>= 1) sc += __shfl_down(sc, off);
          if (lane == 0) ysc[b*NN + i] = sc / pnv;
        }
      }
      __threadfence();
      grid.sync();
      // ============ pool (natural grid 128) ============
      for (int pb = blk; pb < 128; pb += G){
        int r8b = pb & 7, tt = pb >> 3;
        int b = r8b + 8*(tt >> 2), xx = tt & 3;
        float* yk = &t[0][0];
        for (int j = tid; j < NN; j += 256)
          yk[j] = (m[b*NN + j] > 0.f) ? ysc[b*NN + j] : INFINITY;
        __syncthreads();
        int n = ncur[s*BB + b];
        int nr_ = (int)((float)n * RMC);   // exact JAX semantics
        int i = xx*256 + tid;
        float myv = (i < NN) ? yk[i] : INFINITY;
        int cn = 0;
        const float4* yk4 = (const float4*)yk;
        #pragma unroll 5
        for (int q = 0; q < 250; q++){
          float4 v = yk4[q];
          int j0 = q*4;
          cn += (int)((v.x < myv) || (v.x == myv && j0     < i));
          cn += (int)((v.y < myv) || (v.y == myv && j0 + 1 < i));
          cn += (int)((v.z < myv) || (v.z == myv && j0 + 2 < i));
          cn += (int)((v.w < myv) || (v.w == myv && j0 + 3 < i));
        }
        if (i < NN){
          bool keep = (cn >= nr_) && (m[b*NN + i] > 0.f);
          m[b*NN + i]    = keep ? 1.0f : 0.0f;
          gate[b*NN + i] = keep ? tanhf(ysc[b*NN + i]) : 0.0f;
        }
        if (xx == 0 && tid == 0) ncur[(s+1)*BB + b] = n - nr_;
        __syncthreads();                   // yk reuse safety across pb iters
      }
      __threadfence();
      grid.sync();
      // ============ deg (natural grid 128) ============
      for (int pb = blk; pb < 128; pb += G){
        int r8b = pb & 7, tt = pb >> 3;
        int b = r8b + 8*(tt >> 2), xx = tt & 3;
        float* ml = &t[0][0];
        for (int i2 = tid; i2 < NN; i2 += 256) ml[i2] = m[b*NN + i2];
        __syncthreads();
        int j = xx*250 + tid;
        if (tid < 250){
          const short* r = idx + ((size_t)b*NN + j)*CAP;
          int n = cnt[b*NN + j];
          float s0=0.f, s1=0.f, s2=0.f, s3=0.f;
          int k = 0;
          for (; k+4 <= n; k += 4){
            s0 += ml[r[k]]; s1 += ml[r[k+1]]; s2 += ml[r[k+2]]; s3 += ml[r[k+3]];
          }
          for (; k < n; k++) s0 += ml[r[k]];
          float Dv = 1.0f / sqrtf(((s0+s1)+(s2+s3)) + 1.0f + 1e-5f);
          D[b*NN + j]  = Dv;
          dg[b*NN + j] = Dv * gate[b*NN + j];
        }
        __syncthreads();                   // ml reuse safety
      }
      __threadfence();
      grid.sync();
    }
  }
  // ============ fmax (natural grid 256) ============
  for (int pb = blk; pb < 256; pb += G){
    int r8b = pb & 7, tt = pb >> 3;
    int b = r8b + 8*(tt >> 3), sx = tt & 7;
    if (tid < 128){
      int c = tid;
      float mx = 0.f;
      int i0 = sx*125;
      for (int i = i0; i < i0+125; i++){
        if (m[b*NN + i] != 0.f)
          mx = fmaxf(mx, H[((size_t)b*NN + i)*CC + c]);
      }
      part[((size_t)b*8 + sx)*CC + c] = mx;
    }
  }
  __threadfence();
  grid.sync();
  // ============ fc (natural grid 32) ============
  for (int pb = blk; pb < 32; pb += G){
    int b = pb;
    float* gg = &t[0][0];
    if (tid < 128){
      float mx = 0.f;
      #pragma unroll
      for (int s2 = 0; s2 < 8; s2++) mx = fmaxf(mx, part[((size_t)b*8 + s2)*CC + tid]);
      gg[tid] = mx;
    }
    __syncthreads();
    if (tid < OO){
      float acc = bfc[tid];
      for (int c2 = 0; c2 < FF; c2++) acc += gg[c2]*Wfc[tid*FF + c2];
      out[b*OO + tid] = acc;
    }
    __syncthreads();
  }
}

extern "C" void kernel_launch(void* const* d_in, const int* in_sizes, int n_in,
                              void* d_out, int out_size, void* d_ws, size_t ws_size,
                              hipStream_t stream) {
  const float* x    = (const float*)d_in[0];
  const float* A    = (const float*)d_in[1];
  const float* mask = (const float*)d_in[2];
  const int*   Nn   = (const int*)  d_in[3];
  const float* W0   = (const float*)d_in[4];
  const float* b0   = (const float*)d_in[5];
  const float* W1   = (const float*)d_in[6];
  const float* b1   = (const float*)d_in[7];
  const float* W2   = (const float*)d_in[8];
  const float* b2   = (const float*)d_in[9];
  const float* p0   = (const float*)d_in[10];
  const float* p1   = (const float*)d_in[11];
  const float* Wfc  = (const float*)d_in[12];
  const float* bfc  = (const float*)d_in[13];
  float* out = (float*)d_out;

  // workspace carve (~42 MB)
  char* w = (char*)d_ws;
  float* H   = (float*)w; w += (size_t)BB*NN*CC*4;      // 16.38 MB (ping)
  float* H2  = (float*)w; w += (size_t)BB*NN*CC*4;      // 16.38 MB (pong)
  short* idx = (short*)w; w += (size_t)BB*NN*CAP*2;     // 8.19 MB
  float* Wt  = (float*)w; w += (size_t)3*FF*CC*4;       // 192 KB
  float* part= (float*)w; w += (size_t)8*BB*CC*4;       // 131 KB
  int*   cnt = (int*)w;   w += (size_t)BB*NN*4;
  float* D   = (float*)w; w += (size_t)BB*NN*4;
  float* m   = (float*)w; w += (size_t)BB*NN*4;
  float* ysc = (float*)w; w += (size_t)BB*NN*4;
  float* gate= (float*)w; w += (size_t)BB*NN*4;
  float* dg  = (float*)w; w += (size_t)BB*NN*4;
  int*   ncur= (int*)w;   w += 3*BB*sizeof(int);        // ping-pong slots
  float* pn  = (float*)w; w += 64;

  // CSR + all pre-work in one dispatch
  k_csr<<<32032, 64, 0, stream>>>(A, mask, Nn, p0, p1, W0, W1, W2,
                                  idx, cnt, D, dg, m, gate, ncur, pn, Wt);

  // grid size for co-residency (cooperative requirement); 256 CUs on MI355X
  static int G_cached = 0;
  if (G_cached == 0){
    int nb_ = 0;
    hipOccupancyMaxActiveBlocksPerMultiprocessor(&nb_, k_mono, 256, 0);
    if (nb_ < 1) nb_ = 1;
    long long Gl = (long long)nb_ * 256;
    G_cached = (Gl > 800) ? 800 : (int)Gl;
  }
  int G = G_cached;

  void* args[] = { (void*)&x, (void*)&H, (void*)&H2, (void*)&idx, (void*)&cnt,
                   (void*)&D, (void*)&dg, (void*)&m, (void*)&gate, (void*)&Wt,
                   (void*)&b0, (void*)&b1, (void*)&b2, (void*)&p0, (void*)&p1,
                   (void*)&pn, (void*)&ncur, (void*)&ysc, (void*)&part,
                   (void*)&Wfc, (void*)&bfc, (void*)&out, (void*)&G };
  hipLaunchCooperativeKernel((void*)k_mono, dim3(G), dim3(256), args, 0, stream);
}

// Round 12
// 616.477 us; speedup vs baseline: 4.9086x; 4.9086x over previous
//
#include <hip/hip_runtime.h>
#include <math.h>

#define BB 32
#define NN 1000
#define CC 128
#define FF 128
#define OO 64
#define CAP 128
#define NB 40

// exact replica of JAX's np.float32(1.0 - 0.8) = 0.20000000298023224f
#define RMC ((float)(1.0 - 0.8))

// ======== R22: CHUNKED-LDS AGGREGATION (attack the L3 random-BW roofline) ====
// Surviving model after R1-R11 eliminations: cold aggregation = 327-365MB of
// random 512B h-row reads / 66us = ~5.5TB/s = L3 random service ceiling.
// Parallelism/prefetch/pinning can't add L3 BW; only fewer random bytes can.
// k_aggc: block (b, 16-col chunk, row-quarter) stages the chunk of ALL 1000
// source rows into LDS (sequential, 64MB/stage total), then gathers from LDS.
// Reduction tree replicated EXACTLY (8-way position-mod-8 split + fixed
// combine) -> bit-identical T. k_lin restored as R4-verified standalone.

// ---- CSR build + stage-1 D/dg + fused pre-work (blocks with i==NN) ----
__global__ void k_csr(const float* __restrict__ A, const float* __restrict__ mask,
                      const int* __restrict__ Nn,
                      const float* __restrict__ p0, const float* __restrict__ p1,
                      const float* __restrict__ W0, const float* __restrict__ W1,
                      const float* __restrict__ W2,
                      short* __restrict__ idx, int* __restrict__ cnt,
                      float* __restrict__ D, float* __restrict__ dg,
                      float* __restrict__ m, float* __restrict__ gate,
                      int* __restrict__ ncur0, float* __restrict__ pn,
                      float* __restrict__ Wt){
  int blk = blockIdx.x, lane = threadIdx.x;   // grid 32032, block = 64 (one wave)
  int r8 = blk & 7, t = blk >> 3;             // t 0..4003
  int b = r8 + 8*(t/1001), i = t % 1001;      // XCD-spread decode
  if (i == NN){                            // ---- 32 pre-work blocks ----
    for (int j = lane; j < NN; j += 64){
      float v = mask[b*NN + j]; m[b*NN + j] = v; gate[b*NN + j] = v;
    }
    if (lane == 0) ncur0[b] = Nn[b];
    if (b == 0 && lane == 1){ float s=0.f; for(int c=0;c<FF;c++) s += p0[c]*p0[c]; pn[0] = sqrtf(s); }
    if (b == 1 && lane == 1){ float s=0.f; for(int c=0;c<FF;c++) s += p1[c]*p1[c]; pn[1] = sqrtf(s); }
    // Wt[s][c][f] = W[s][f][c]; 3*FF*CC = 49152 elems, 1536 per block
    for (int e = b*1536 + lane; e < (b+1)*1536; e += 64){
      int s = e / (FF*CC), rem = e % (FF*CC);
      int c = rem >> 7, f = rem & 127;
      const float* W = (s == 0) ? W0 : (s == 1) ? W1 : W2;
      Wt[(size_t)s*FF*CC + rem] = W[f*CC + c];
    }
    return;
  }
  if (mask[b*NN + i] == 0.f){              // A row is all-zero (A pre-masked)
    if (lane == 0){
      cnt[b*NN + i] = 0;
      D[b*NN + i]  = 1.0f / sqrtf(1.0f + 1e-5f);
      dg[b*NN + i] = 0.f;
    }
    return;
  }
  const float4* row = (const float4*)(A + ((size_t)b*NN + i)*NN);
  short* out = idx + ((size_t)b*NN + i)*CAP;
  int count = 0;
  for (int base = 0; base < 250; base += 64){               // 1000 = 250 float4
    int q = base + lane;
    float4 v;
    if (q < 250) v = row[q]; else { v.x=v.y=v.z=v.w=0.f; }
    int lc = (v.x!=0.f) + (v.y!=0.f) + (v.z!=0.f) + (v.w!=0.f);
    int pre = lc;
    #pragma unroll
    for (int off = 1; off < 64; off <<= 1){
      int t2 = __shfl_up(pre, off);
      if (lane >= off) pre += t2;
    }
    int tot = __shfl(pre, 63);
    pre -= lc;                                              // exclusive prefix
    int slot = count + pre;
    int j = q*4;
    if (v.x!=0.f && slot < CAP) out[slot++] = (short)j;
    if (v.y!=0.f && slot < CAP) out[slot++] = (short)(j+1);
    if (v.z!=0.f && slot < CAP) out[slot++] = (short)(j+2);
    if (v.w!=0.f && slot < CAP) out[slot++] = (short)(j+3);
    count += tot;
  }
  if (lane == 0){
    int cn = (count < CAP) ? count : CAP;
    cnt[b*NN + i] = cn;
    float Dv = 1.0f / sqrtf((float)cn + 1.0f + 1e-5f);
    D[b*NN + i]  = Dv;
    dg[b*NN + i] = Dv;                   // mask_i == 1 here
  }
}

// ---- R22 chunked aggregation: T chunk = exact replica of agglin phase-1 ----
// block = (b, ck, rq): stages h[b][:, 16ck..16ck+15] for ALL 1000 rows into
// LDS, processes rows rq*250..+249. Wave = 1 row: 64 lanes = 16 cols x 4
// edge-slots. bA/bB = position-mod-8 partial sums (ascending, identical chain
// to the original a0..a3 split); two shfl_xor rebuild the exact combine tree.
__global__ void k_aggc(const short* __restrict__ idx, const int* __restrict__ cnt,
                       const float* __restrict__ D, const float* __restrict__ dg,
                       const float* __restrict__ m, const float* __restrict__ gate,
                       const float* __restrict__ h, float* __restrict__ T){
  __shared__ float hs[NN*16];            // 62.5 KB: 16-col chunk of all rows
  __shared__ int   nb[8][CAP];           // per-wave compacted j*16 (4 KB)
  __shared__ float dn[8][CAP];           // (4 KB)
  int blk = blockIdx.x, tid = threadIdx.x;  // grid 1024, block 512 (8 waves)
  int r8 = blk & 7;
  int b  = r8 + 8*((blk >> 3) & 3);      // XCD pin: blk%8 == b&7
  int ck = (blk >> 5) & 7;               // 0..7 column chunk
  int rq = blk >> 8;                     // 0..3 row quarter
  int c0 = ck*16;
  int w = tid >> 6, lane = tid & 63;
  int c = lane & 15, s = lane >> 4;      // col-in-chunk, edge-slot 0..3
  const float* hb = h + (size_t)b*NN*CC;
  int*   nbw = nb[w];
  float* dnw = dn[w];
  // ---- stage chunk: sequential 64 KB read (the L3-friendly path) ----
  {
    const float* src = hb + c0;
    float4* hs4 = (float4*)hs;
    for (int q = tid; q < NN*4; q += 512){
      int row = q >> 2, f4 = q & 3;
      hs4[q] = *(const float4*)(src + (size_t)row*CC + f4*4);
    }
  }
  __syncthreads();
  // ---- rows rq*250 .. rq*250+249, striped across the 8 waves ----
  for (int rr = w; rr < 250; rr += 8){
    int ib = rq*250 + rr;                // absolute row 0..999
    if (m[b*NN + ib] == 0.f){            // masked target: T chunk is zero
      if (s == 0) T[((size_t)b*NN + ib)*CC + c0 + c] = 0.f;
      continue;                          // wave-uniform
    }
    int n = cnt[b*NN + ib];
    const short* r = idx + ((size_t)b*NN + ib)*CAP;
    // --- compaction: verbatim 64-lane ballot (keep dn != 0, order kept) ---
    int j0 = 0; float d0 = 0.f; bool k0 = false;
    if (lane < n){ j0 = (int)r[lane]; d0 = dg[b*NN + j0]; k0 = (d0 != 0.f); }
    unsigned long long bal = __ballot(k0);
    int pre = __popcll(bal & ((1ull << lane) - 1ull));
    if (k0){ nbw[pre] = j0*16; dnw[pre] = d0; }
    int nlive = __popcll(bal);
    if (n > 64){                         // wave-uniform branch
      int e = lane + 64; int j1 = 0; float d1 = 0.f; bool k1 = false;
      if (e < n){ j1 = (int)r[e]; d1 = dg[b*NN + j1]; k1 = (d1 != 0.f); }
      unsigned long long bal1 = __ballot(k1);
      int pre1 = __popcll(bal1 & ((1ull << lane) - 1ull));
      if (k1){ nbw[nlive + pre1] = j1*16; dnw[nlive + pre1] = d1; }
      nlive += __popcll(bal1);
    }
    int np = (nlive + 7) & ~7;           // pad to 8 (same zero-contributions)
    if (lane < np - nlive){ nbw[nlive + lane] = 0; dnw[nlive + lane] = 0.f; }
    __builtin_amdgcn_wave_barrier();     // fence: LDS writes before reads
    // --- walk: bA = sum over pos≡s (mod 8) ascending, bB = pos≡s+4 ---
    float bA = 0.f, bB = 0.f;
    for (int k = 0; k < np; k += 8){
      float dA = dnw[k + s],     hA = hs[nbw[k + s]     + c];
      float dB = dnw[k + s + 4], hB = hs[nbw[k + s + 4] + c];
      bA += dA*hA;
      bB += dB*hB;
    }
    // exact original tree: Y = ((b0+b2)+(b4+b6)) + ((b1+b3)+(b5+b7))
    float u  = bA + __shfl_xor(bA, 32);  // s^2 partner: (b_s + b_{s+2})
    float v  = bB + __shfl_xor(bB, 32);  //               (b_{s+4} + b_{s+6})
    float e2 = u + v;                    // s=0: Y_g0 ; s=1: Y_g1
    float Y  = e2 + __shfl_xor(e2, 16);  // s^1 partner: Y_g0 + Y_g1 on s=0
    float Di = D[b*NN + ib];
    float gi = gate[b*NN + ib];
    if (s == 0){
      float hv = hs[ib*16 + c];
      T[((size_t)b*NN + ib)*CC + c0 + c] = Di*Y + Di*Di*(gi*hv);
    }
  }
}

// ---- H = relu(T @ W^T + b)*m ----
// FROZEN R3 GEMM body (R4-verified standalone with pinned decode). Empirical
// law (3 confirmations): ANY decoration flips the allocator to spills. Do not
// decorate.
__global__ void k_lin(const float* __restrict__ T, const float* __restrict__ m,
                      const float* __restrict__ Wt,   // [cc][f] transposed
                      const float* __restrict__ bias, float* __restrict__ Hout){
  __shared__ float t[NB][CC];              // 20.5 KB
  int blk = blockIdx.x, tid = threadIdx.x; // grid 800, block = 256
  int r8 = blk & 7, tq = blk >> 3;         // tq 0..99
  int b = r8 + 8*(tq/25);                  // pin: blk%8 == b&7
  int i0 = (tq % 25) * NB;
  const float4* Tg = (const float4*)(T + ((size_t)b*NN + i0)*CC);
  float4* tl = (float4*)&t[0][0];
  #pragma unroll
  for (int e = 0; e < 5; e++) tl[tid + e*256] = Tg[tid + e*256];  // 1280 float4
  __syncthreads();
  int fg = tid & 31;                       // 4 consecutive f per thread
  int nr = tid >> 5;                       // 0..7 node-row
  float acc[5][4];
  float4 bi = ((const float4*)bias)[fg];
  #pragma unroll
  for (int n5 = 0; n5 < 5; n5++){
    acc[n5][0]=bi.x; acc[n5][1]=bi.y; acc[n5][2]=bi.z; acc[n5][3]=bi.w;
  }
  for (int c4 = 0; c4 < 32; c4++){
    float4 tv[5];
    #pragma unroll
    for (int n5 = 0; n5 < 5; n5++)
      tv[n5] = *((const float4*)&t[nr + n5*8][c4*4]);
    #pragma unroll
    for (int k = 0; k < 4; k++){
      float4 wv = ((const float4*)Wt)[(size_t)(c4*4 + k)*32 + fg];
      #pragma unroll
      for (int n5 = 0; n5 < 5; n5++){
        float tvv = (k==0) ? tv[n5].x : (k==1) ? tv[n5].y : (k==2) ? tv[n5].z : tv[n5].w;
        acc[n5][0] += tvv*wv.x; acc[n5][1] += tvv*wv.y;
        acc[n5][2] += tvv*wv.z; acc[n5][3] += tvv*wv.w;
      }
    }
  }
  #pragma unroll
  for (int n5 = 0; n5 < 5; n5++){
    int i = i0 + nr + n5*8;
    float mi = m[b*NN + i];
    float4 o4;
    o4.x = fmaxf(acc[n5][0], 0.f)*mi;
    o4.y = fmaxf(acc[n5][1], 0.f)*mi;
    o4.z = fmaxf(acc[n5][2], 0.f)*mi;
    o4.w = fmaxf(acc[n5][3], 0.f)*mi;
    ((float4*)&Hout[((size_t)b*NN + i)*CC])[fg] = o4;
  }
}

// ---------------- pool scores y_i = (H_i . p) / |p| ----------------
__global__ void k_score(const float* __restrict__ H, const float* __restrict__ p,
                        const float* __restrict__ pn, float* __restrict__ y){
  int blk = blockIdx.x, lane = threadIdx.x;  // grid 32000, block = 64
  int r8 = blk & 7, t = blk >> 3;            // t 0..3999
  int b = r8 + 8*(t/1000), i = t % 1000;
  const float* hrow = H + ((size_t)b*NN + i)*CC;
  float s = hrow[lane]*p[lane] + hrow[lane+64]*p[lane+64];
  for (int off = 32; off > 0; off >>= 1) s += __shfl_down(s, off);
  if (lane == 0) y[b*NN + i] = s / pn[0];
}

// ---------------- top-k pool: 1 node/thread, float4 LDS scan, ping-pong ncur ----------------
__global__ void k_pool(const float* __restrict__ y, float* __restrict__ m,
                       const int* __restrict__ ncur_in, int* __restrict__ ncur_out,
                       float* __restrict__ gate){
  __shared__ float yk[NN];
  int blk = blockIdx.x, tid = threadIdx.x;   // grid 128, block = 256
  int r8 = blk & 7, t = blk >> 3;            // t 0..15
  int b = r8 + 8*(t >> 2), xx = t & 3;
  int i = xx*256 + tid;
  for (int j = tid; j < NN; j += 256)
    yk[j] = (m[b*NN + j] > 0.f) ? y[b*NN + j] : INFINITY;
  __syncthreads();
  int n = ncur_in[b];
  int nr = (int)((float)n * RMC);          // exact JAX semantics (f32 mult, trunc)
  float myv = (i < NN) ? yk[i] : INFINITY;
  int cnt = 0;
  const float4* yk4 = (const float4*)yk;   // broadcast reads: conflict-free
  #pragma unroll 5
  for (int q = 0; q < 250; q++){
    float4 v = yk4[q];
    int j0 = q*4;
    cnt += (int)((v.x < myv) || (v.x == myv && j0     < i));
    cnt += (int)((v.y < myv) || (v.y == myv && j0 + 1 < i));
    cnt += (int)((v.z < myv) || (v.z == myv && j0 + 2 < i));
    cnt += (int)((v.w < myv) || (v.w == myv && j0 + 3 < i));
  }
  if (i < NN){
    bool keep = (cnt >= nr) && (m[b*NN + i] > 0.f);
    m[b*NN + i]    = keep ? 1.0f : 0.0f;
    gate[b*NN + i] = keep ? tanhf(y[b*NN + i]) : 0.0f;
  }
  if (xx == 0 && tid == 0) ncur_out[b] = n - nr;
}

// ---------------- degree from new mask -> D, dg = D*gate ----------------
__global__ void k_deg(const short* __restrict__ idx, const int* __restrict__ cnt,
                      const float* __restrict__ m, const float* __restrict__ gate,
                      float* __restrict__ D, float* __restrict__ dg){
  __shared__ float ml[NN];
  int blk = blockIdx.x, tid = threadIdx.x;   // grid 128, block = 256
  int r8 = blk & 7, t = blk >> 3;            // t 0..15
  int b = r8 + 8*(t >> 2), xx = t & 3;
  for (int i = tid; i < NN; i += 256) ml[i] = m[b*NN + i];
  __syncthreads();
  int j = xx*250 + tid;
  if (tid < 250){
    const short* r = idx + ((size_t)b*NN + j)*CAP;
    int n = cnt[b*NN + j];
    float s0=0.f, s1=0.f, s2=0.f, s3=0.f;
    int k = 0;
    for (; k+4 <= n; k += 4){
      s0 += ml[r[k]]; s1 += ml[r[k+1]]; s2 += ml[r[k+2]]; s3 += ml[r[k+3]];
    }
    for (; k < n; k++) s0 += ml[r[k]];
    float Dv = 1.0f / sqrtf(((s0+s1)+(s2+s3)) + 1.0f + 1e-5f);
    D[b*NN + j]  = Dv;
    dg[b*NN + j] = Dv * gate[b*NN + j];
  }
}

// ---------------- partial global max pool (masked rows skipped; relu => max>=0) ----------------
__global__ void k_fmax(const float* __restrict__ H, const float* __restrict__ m,
                       float* __restrict__ part){
  int blk = blockIdx.x, c = threadIdx.x;     // grid 256, block = 128
  int r8 = blk & 7, t = blk >> 3;            // t 0..31
  int b = r8 + 8*(t >> 3), sx = t & 7;
  float mx = 0.f;
  int i0 = sx*125;
  for (int i = i0; i < i0+125; i++){
    if (m[b*NN + i] != 0.f)
      mx = fmaxf(mx, H[((size_t)b*NN + i)*CC + c]);
  }
  part[((size_t)b*8 + sx)*CC + c] = mx;
}

// ---------------- combine partial maxima + FC ----------------
__global__ void k_fc(const float* __restrict__ part, const float* __restrict__ Wfc,
                     const float* __restrict__ bfc, float* __restrict__ out){
  __shared__ float g[FF];
  int b = blockIdx.x, tid = threadIdx.x;   // block = 128
  float mx = 0.f;
  #pragma unroll
  for (int s = 0; s < 8; s++) mx = fmaxf(mx, part[((size_t)b*8 + s)*CC + tid]);
  g[tid] = mx;
  __syncthreads();
  if (tid < OO){
    float acc = bfc[tid];
    for (int c = 0; c < FF; c++) acc += g[c]*Wfc[tid*FF + c];
    out[b*OO + tid] = acc;
  }
}

extern "C" void kernel_launch(void* const* d_in, const int* in_sizes, int n_in,
                              void* d_out, int out_size, void* d_ws, size_t ws_size,
                              hipStream_t stream) {
  const float* x    = (const float*)d_in[0];
  const float* A    = (const float*)d_in[1];
  const float* mask = (const float*)d_in[2];
  const int*   Nn   = (const int*)  d_in[3];
  const float* W0   = (const float*)d_in[4];
  const float* b0   = (const float*)d_in[5];
  const float* W1   = (const float*)d_in[6];
  const float* b1   = (const float*)d_in[7];
  const float* W2   = (const float*)d_in[8];
  const float* b2   = (const float*)d_in[9];
  const float* p0   = (const float*)d_in[10];
  const float* p1   = (const float*)d_in[11];
  const float* Wfc  = (const float*)d_in[12];
  const float* bfc  = (const float*)d_in[13];
  float* out = (float*)d_out;

  // workspace carve (~58 MB)
  char* w = (char*)d_ws;
  float* H   = (float*)w; w += (size_t)BB*NN*CC*4;      // 16.38 MB (ping)
  float* H2  = (float*)w; w += (size_t)BB*NN*CC*4;      // 16.38 MB (pong)
  float* T   = (float*)w; w += (size_t)BB*NN*CC*4;      // 16.38 MB
  short* idx = (short*)w; w += (size_t)BB*NN*CAP*2;     // 8.19 MB
  float* Wt  = (float*)w; w += (size_t)3*FF*CC*4;       // 192 KB
  float* part= (float*)w; w += (size_t)8*BB*CC*4;       // 131 KB
  int*   cnt = (int*)w;   w += (size_t)BB*NN*4;
  float* D   = (float*)w; w += (size_t)BB*NN*4;
  float* m   = (float*)w; w += (size_t)BB*NN*4;
  float* ysc = (float*)w; w += (size_t)BB*NN*4;
  float* gate= (float*)w; w += (size_t)BB*NN*4;
  float* dg  = (float*)w; w += (size_t)BB*NN*4;
  int*   ncur= (int*)w;   w += 3*BB*sizeof(int);        // ping-pong slots
  float* pn  = (float*)w; w += 64;

  // CSR + all pre-work in one dispatch
  k_csr<<<32032, 64, 0, stream>>>(A, mask, Nn, p0, p1, W0, W1, W2,
                                  idx, cnt, D, dg, m, gate, ncur, pn, Wt);

  // ---- stage 1: x -> T -> H ----
  k_aggc<<<1024, 512, 0, stream>>>(idx, cnt, D, dg, m, gate, x, T);
  k_lin<<<800, 256, 0, stream>>>(T, m, Wt + 0*FF*CC, b0, H);
  k_score<<<32000, 64, 0, stream>>>(H, p0, pn + 0, ysc);
  k_pool<<<128, 256, 0, stream>>>(ysc, m, ncur + 0*BB, ncur + 1*BB, gate);
  k_deg<<<128, 256, 0, stream>>>(idx, cnt, m, gate, D, dg);

  // ---- stage 2: H -> T -> H2 ----
  k_aggc<<<1024, 512, 0, stream>>>(idx, cnt, D, dg, m, gate, H, T);
  k_lin<<<800, 256, 0, stream>>>(T, m, Wt + 1*FF*CC, b1, H2);
  k_score<<<32000, 64, 0, stream>>>(H2, p1, pn + 1, ysc);
  k_pool<<<128, 256, 0, stream>>>(ysc, m, ncur + 1*BB, ncur + 2*BB, gate);
  k_deg<<<128, 256, 0, stream>>>(idx, cnt, m, gate, D, dg);

  // ---- stage 3: H2 -> T -> H ----
  k_aggc<<<1024, 512, 0, stream>>>(idx, cnt, D, dg, m, gate, H2, T);
  k_lin<<<800, 256, 0, stream>>>(T, m, Wt + 2*FF*CC, b2, H);

  // ---- global max pool + FC ----
  k_fmax<<<256, 128, 0, stream>>>(H, m, part);
  k_fc<<<BB, 128, 0, stream>>>(part, Wfc, bfc, out);
}

// Round 13
// 462.536 us; speedup vs baseline: 6.5423x; 1.3328x over previous
//
#include <hip/hip_runtime.h>
#include <math.h>

#define BB 32
#define NN 1000
#define CC 128
#define FF 128
#define OO 64
#define CAP 128
#define NB 40

// exact replica of JAX's np.float32(1.0 - 0.8) = 0.20000000298023224f
#define RMC ((float)(1.0 - 0.8))

// ======== R23: R7 BASE + GATHER 8->16 LOADS IN FLIGHT + deg short4 ========
// 13-round ledger: the ONLY positive-delta intervention was R4's gather
// unroll 4->8 in-flight loads (-15us). R7 (more waves) null => binding
// resource is PER-WAVE miss-level parallelism, not wave count. This round
// doubles it again: 16 float4 loads in flight (np padded to 32; body =
// exact concatenation of two consecutive old iterations => bit-exact,
// zero-pads contribute +0.0 as before). k_deg idx walk vectorized to
// short4 (same position->accumulator mapping => bit-exact).

// ---- CSR build + stage-1 D/dg + fused pre-work (blocks with i==NN) ----
__global__ void k_csr(const float* __restrict__ A, const float* __restrict__ mask,
                      const int* __restrict__ Nn,
                      const float* __restrict__ p0, const float* __restrict__ p1,
                      const float* __restrict__ W0, const float* __restrict__ W1,
                      const float* __restrict__ W2,
                      short* __restrict__ idx, int* __restrict__ cnt,
                      float* __restrict__ D, float* __restrict__ dg,
                      float* __restrict__ m, float* __restrict__ gate,
                      int* __restrict__ ncur0, float* __restrict__ pn,
                      float* __restrict__ Wt){
  int blk = blockIdx.x, lane = threadIdx.x;   // grid 32032, block = 64 (one wave)
  int r8 = blk & 7, t = blk >> 3;             // t 0..4003
  int b = r8 + 8*(t/1001), i = t % 1001;      // XCD-spread decode
  if (i == NN){                            // ---- 32 pre-work blocks ----
    for (int j = lane; j < NN; j += 64){
      float v = mask[b*NN + j]; m[b*NN + j] = v; gate[b*NN + j] = v;
    }
    if (lane == 0) ncur0[b] = Nn[b];
    if (b == 0 && lane == 1){ float s=0.f; for(int c=0;c<FF;c++) s += p0[c]*p0[c]; pn[0] = sqrtf(s); }
    if (b == 1 && lane == 1){ float s=0.f; for(int c=0;c<FF;c++) s += p1[c]*p1[c]; pn[1] = sqrtf(s); }
    // Wt[s][c][f] = W[s][f][c]; 3*FF*CC = 49152 elems, 1536 per block
    for (int e = b*1536 + lane; e < (b+1)*1536; e += 64){
      int s = e / (FF*CC), rem = e % (FF*CC);
      int c = rem >> 7, f = rem & 127;
      const float* W = (s == 0) ? W0 : (s == 1) ? W1 : W2;
      Wt[(size_t)s*FF*CC + rem] = W[f*CC + c];
    }
    return;
  }
  if (mask[b*NN + i] == 0.f){              // A row is all-zero (A pre-masked)
    if (lane == 0){
      cnt[b*NN + i] = 0;
      D[b*NN + i]  = 1.0f / sqrtf(1.0f + 1e-5f);
      dg[b*NN + i] = 0.f;
    }
    return;
  }
  const float4* row = (const float4*)(A + ((size_t)b*NN + i)*NN);
  short* out = idx + ((size_t)b*NN + i)*CAP;
  int count = 0;
  for (int base = 0; base < 250; base += 64){               // 1000 = 250 float4
    int q = base + lane;
    float4 v;
    if (q < 250) v = row[q]; else { v.x=v.y=v.z=v.w=0.f; }
    int lc = (v.x!=0.f) + (v.y!=0.f) + (v.z!=0.f) + (v.w!=0.f);
    int pre = lc;
    #pragma unroll
    for (int off = 1; off < 64; off <<= 1){
      int t2 = __shfl_up(pre, off);
      if (lane >= off) pre += t2;
    }
    int tot = __shfl(pre, 63);
    pre -= lc;                                              // exclusive prefix
    int slot = count + pre;
    int j = q*4;
    if (v.x!=0.f && slot < CAP) out[slot++] = (short)j;
    if (v.y!=0.f && slot < CAP) out[slot++] = (short)(j+1);
    if (v.z!=0.f && slot < CAP) out[slot++] = (short)(j+2);
    if (v.w!=0.f && slot < CAP) out[slot++] = (short)(j+3);
    count += tot;
  }
  if (lane == 0){
    int cn = (count < CAP) ? count : CAP;
    cnt[b*NN + i] = cn;
    float Dv = 1.0f / sqrtf((float)cn + 1.0f + 1e-5f);
    D[b*NN + i]  = Dv;
    dg[b*NN + i] = Dv;                   // mask_i == 1 here
  }
}

// ---- FUSED: T-tile into LDS (phase 1, 8 waves x 5 rows, 16-deep gather)
//      + frozen GEMM (phase 2, waves 0-3) ----
// Spill tripwire: this kernel in top-5 with WRITE_SIZE >> 16MB => revert.
__global__ void k_agglin(const short* __restrict__ idx, const int* __restrict__ cnt,
                         const float* __restrict__ D, const float* __restrict__ dg,
                         const float* __restrict__ m, const float* __restrict__ gate,
                         const float* __restrict__ h,
                         const float* __restrict__ Wt,   // [cc][f] transposed
                         const float* __restrict__ bias, float* __restrict__ Hout){
  __shared__ float t[NB][CC];              // 20.5 KB (the old T staging buffer)
  __shared__ int   nb[8][CAP];             // per-wave gather scratch (4 KB)
  __shared__ float dn[8][CAP];             // (4 KB)
  int blk = blockIdx.x, tid = threadIdx.x; // grid 800, block = 512 (8 waves)
  int r8 = blk & 7, tq = blk >> 3;         // tq 0..99
  int b = r8 + 8*(tq/25);
  int i0 = (tq % 25) * NB;
  int w = tid >> 6, lane = tid & 63;
  int g = lane >> 5, l32 = lane & 31;
  const float* hb = h + (size_t)b*NN*CC;
  int*   nbw = nb[w];
  float* dnw = dn[w];
  // ================= phase 1: aggregate 40 rows into t (5 rows/wave) ====
  for (int q = 0; q < 5; q++){             // wave w owns local rows w, w+8, ... w+32
    int lr = q*8 + w;
    int i  = i0 + lr;
    if (m[b*NN + i] == 0.f){               // masked target: T row is zero
      if (g == 0){ float4 z = {0.f,0.f,0.f,0.f}; *(float4*)&t[lr][l32<<2] = z; }
      continue;                            // wave-uniform
    }
    int n = cnt[b*NN + i];
    const short* r = idx + ((size_t)b*NN + i)*CAP;
    // --- wave-level order-preserving compaction: keep edges with dn != 0 ---
    int j0 = 0; float d0 = 0.f; bool k0 = false;
    if (lane < n){ j0 = (int)r[lane]; d0 = dg[b*NN + j0]; k0 = (d0 != 0.f); }
    unsigned long long bal = __ballot(k0);
    int pre = __popcll(bal & ((1ull << lane) - 1ull));
    if (k0){ nbw[pre] = j0*CC; dnw[pre] = d0; }
    int nlive = __popcll(bal);
    if (n > 64){                           // wave-uniform branch
      int e = lane + 64; int j1 = 0; float d1 = 0.f; bool k1 = false;
      if (e < n){ j1 = (int)r[e]; d1 = dg[b*NN + j1]; k1 = (d1 != 0.f); }
      unsigned long long bal1 = __ballot(k1);
      int pre1 = __popcll(bal1 & ((1ull << lane) - 1ull));
      if (k1){ nbw[nlive + pre1] = j1*CC; dnw[nlive + pre1] = d1; }
      nlive += __popcll(bal1);
    }
    int np = (nlive + 31) & ~31;           // pad to 32 (CAP=128 safe; zero terms)
    if (lane < np - nlive){ nbw[nlive + lane] = 0; dnw[nlive + lane] = 0.f; }
    __builtin_amdgcn_wave_barrier();       // fence: LDS writes before reads
    // --- branch-free float4 gather, 16 loads/lane in flight.
    //     Body = exact concatenation of two consecutive R7 iterations
    //     (k and k+16) => identical association order, bit-exact. ---
    float4 a0 = {0.f,0.f,0.f,0.f}, a1 = a0, a2 = a0, a3 = a0;
    for (int k = 0; k < np; k += 32){
      int e = k + g;
      float4 v0 = *(const float4*)(hb + nbw[e   ] + (l32<<2));
      float4 v1 = *(const float4*)(hb + nbw[e+ 2] + (l32<<2));
      float4 v2 = *(const float4*)(hb + nbw[e+ 4] + (l32<<2));
      float4 v3 = *(const float4*)(hb + nbw[e+ 6] + (l32<<2));
      float4 v4 = *(const float4*)(hb + nbw[e+ 8] + (l32<<2));
      float4 v5 = *(const float4*)(hb + nbw[e+10] + (l32<<2));
      float4 v6 = *(const float4*)(hb + nbw[e+12] + (l32<<2));
      float4 v7 = *(const float4*)(hb + nbw[e+14] + (l32<<2));
      float4 u0 = *(const float4*)(hb + nbw[e+16] + (l32<<2));
      float4 u1 = *(const float4*)(hb + nbw[e+18] + (l32<<2));
      float4 u2 = *(const float4*)(hb + nbw[e+20] + (l32<<2));
      float4 u3 = *(const float4*)(hb + nbw[e+22] + (l32<<2));
      float4 u4 = *(const float4*)(hb + nbw[e+24] + (l32<<2));
      float4 u5 = *(const float4*)(hb + nbw[e+26] + (l32<<2));
      float4 u6 = *(const float4*)(hb + nbw[e+28] + (l32<<2));
      float4 u7 = *(const float4*)(hb + nbw[e+30] + (l32<<2));
      float e0 = dnw[e],    e1 = dnw[e+ 2], e2 = dnw[e+ 4], e3 = dnw[e+ 6];
      float e4 = dnw[e+ 8], e5 = dnw[e+10], e6 = dnw[e+12], e7 = dnw[e+14];
      float f0 = dnw[e+16], f1 = dnw[e+18], f2 = dnw[e+20], f3 = dnw[e+22];
      float f4 = dnw[e+24], f5 = dnw[e+26], f6 = dnw[e+28], f7 = dnw[e+30];
      // ---- old iteration k (verbatim order) ----
      a0.x += e0*v0.x; a0.y += e0*v0.y; a0.z += e0*v0.z; a0.w += e0*v0.w;
      a1.x += e1*v1.x; a1.y += e1*v1.y; a1.z += e1*v1.z; a1.w += e1*v1.w;
      a2.x += e2*v2.x; a2.y += e2*v2.y; a2.z += e2*v2.z; a2.w += e2*v2.w;
      a3.x += e3*v3.x; a3.y += e3*v3.y; a3.z += e3*v3.z; a3.w += e3*v3.w;
      a0.x += e4*v4.x; a0.y += e4*v4.y; a0.z += e4*v4.z; a0.w += e4*v4.w;
      a1.x += e5*v5.x; a1.y += e5*v5.y; a1.z += e5*v5.z; a1.w += e5*v5.w;
      a2.x += e6*v6.x; a2.y += e6*v6.y; a2.z += e6*v6.z; a2.w += e6*v6.w;
      a3.x += e7*v7.x; a3.y += e7*v7.y; a3.z += e7*v7.z; a3.w += e7*v7.w;
      // ---- old iteration k+16 (verbatim order) ----
      a0.x += f0*u0.x; a0.y += f0*u0.y; a0.z += f0*u0.z; a0.w += f0*u0.w;
      a1.x += f1*u1.x; a1.y += f1*u1.y; a1.z += f1*u1.z; a1.w += f1*u1.w;
      a2.x += f2*u2.x; a2.y += f2*u2.y; a2.z += f2*u2.z; a2.w += f2*u2.w;
      a3.x += f3*u3.x; a3.y += f3*u3.y; a3.z += f3*u3.z; a3.w += f3*u3.w;
      a0.x += f4*u4.x; a0.y += f4*u4.y; a0.z += f4*u4.z; a0.w += f4*u4.w;
      a1.x += f5*u5.x; a1.y += f5*u5.y; a1.z += f5*u5.z; a1.w += f5*u5.w;
      a2.x += f6*u6.x; a2.y += f6*u6.y; a2.z += f6*u6.z; a2.w += f6*u6.w;
      a3.x += f7*u7.x; a3.y += f7*u7.y; a3.z += f7*u7.z; a3.w += f7*u7.w;
    }
    float4 Y;
    Y.x = (a0.x + a1.x) + (a2.x + a3.x);
    Y.y = (a0.y + a1.y) + (a2.y + a3.y);
    Y.z = (a0.z + a1.z) + (a2.z + a3.z);
    Y.w = (a0.w + a1.w) + (a2.w + a3.w);
    Y.x += __shfl_xor(Y.x, 32);            // combine the two 32-lane groups
    Y.y += __shfl_xor(Y.y, 32);
    Y.z += __shfl_xor(Y.z, 32);
    Y.w += __shfl_xor(Y.w, 32);
    float Di = D[b*NN + i];
    float gi = gate[b*NN + i];
    if (g == 0){
      float4 hv = *(const float4*)(hb + (size_t)i*CC + (l32<<2));
      float4 o;
      o.x = Di*Y.x + Di*Di*(gi*hv.x);
      o.y = Di*Y.y + Di*Di*(gi*hv.y);
      o.z = Di*Y.z + Di*Di*(gi*hv.z);
      o.w = Di*Y.w + Di*Di*(gi*hv.w);
      *(float4*)&t[lr][l32<<2] = o;
    }
  }
  __syncthreads();
  // ================= phase 2: FROZEN R3 GEMM body (verbatim, waves 0-3) =====
  if (tid < 256){
    int fg = tid & 31;                     // 4 consecutive f per thread
    int nr = tid >> 5;                     // 0..7 node-row
    float acc[5][4];
    float4 bi = ((const float4*)bias)[fg];
    #pragma unroll
    for (int n5 = 0; n5 < 5; n5++){
      acc[n5][0]=bi.x; acc[n5][1]=bi.y; acc[n5][2]=bi.z; acc[n5][3]=bi.w;
    }
    for (int c4 = 0; c4 < 32; c4++){
      float4 tv[5];
      #pragma unroll
      for (int n5 = 0; n5 < 5; n5++)
        tv[n5] = *((const float4*)&t[nr + n5*8][c4*4]);
      #pragma unroll
      for (int k = 0; k < 4; k++){
        float4 wv = ((const float4*)Wt)[(size_t)(c4*4 + k)*32 + fg];
        #pragma unroll
        for (int n5 = 0; n5 < 5; n5++){
          float tvv = (k==0) ? tv[n5].x : (k==1) ? tv[n5].y : (k==2) ? tv[n5].z : tv[n5].w;
          acc[n5][0] += tvv*wv.x; acc[n5][1] += tvv*wv.y;
          acc[n5][2] += tvv*wv.z; acc[n5][3] += tvv*wv.w;
        }
      }
    }
    #pragma unroll
    for (int n5 = 0; n5 < 5; n5++){
      int i = i0 + nr + n5*8;
      float mi = m[b*NN + i];
      float4 o4;
      o4.x = fmaxf(acc[n5][0], 0.f)*mi;
      o4.y = fmaxf(acc[n5][1], 0.f)*mi;
      o4.z = fmaxf(acc[n5][2], 0.f)*mi;
      o4.w = fmaxf(acc[n5][3], 0.f)*mi;
      ((float4*)&Hout[((size_t)b*NN + i)*CC])[fg] = o4;
    }
  }
}

// ---------------- pool scores y_i = (H_i . p) / |p| ----------------
__global__ void k_score(const float* __restrict__ H, const float* __restrict__ p,
                        const float* __restrict__ pn, float* __restrict__ y){
  int blk = blockIdx.x, lane = threadIdx.x;  // grid 32000, block = 64
  int r8 = blk & 7, t = blk >> 3;            // t 0..3999
  int b = r8 + 8*(t/1000), i = t % 1000;
  const float* hrow = H + ((size_t)b*NN + i)*CC;
  float s = hrow[lane]*p[lane] + hrow[lane+64]*p[lane+64];
  for (int off = 32; off > 0; off >>= 1) s += __shfl_down(s, off);
  if (lane == 0) y[b*NN + i] = s / pn[0];
}

// ---------------- top-k pool: 1 node/thread, float4 LDS scan, ping-pong ncur ----------------
__global__ void k_pool(const float* __restrict__ y, float* __restrict__ m,
                       const int* __restrict__ ncur_in, int* __restrict__ ncur_out,
                       float* __restrict__ gate){
  __shared__ float yk[NN];
  int blk = blockIdx.x, tid = threadIdx.x;   // grid 128, block = 256
  int r8 = blk & 7, t = blk >> 3;            // t 0..15
  int b = r8 + 8*(t >> 2), xx = t & 3;
  int i = xx*256 + tid;
  for (int j = tid; j < NN; j += 256)
    yk[j] = (m[b*NN + j] > 0.f) ? y[b*NN + j] : INFINITY;
  __syncthreads();
  int n = ncur_in[b];
  int nr = (int)((float)n * RMC);          // exact JAX semantics (f32 mult, trunc)
  float myv = (i < NN) ? yk[i] : INFINITY;
  int cnt = 0;
  const float4* yk4 = (const float4*)yk;   // broadcast reads: conflict-free
  #pragma unroll 5
  for (int q = 0; q < 250; q++){
    float4 v = yk4[q];
    int j0 = q*4;
    cnt += (int)((v.x < myv) || (v.x == myv && j0     < i));
    cnt += (int)((v.y < myv) || (v.y == myv && j0 + 1 < i));
    cnt += (int)((v.z < myv) || (v.z == myv && j0 + 2 < i));
    cnt += (int)((v.w < myv) || (v.w == myv && j0 + 3 < i));
  }
  if (i < NN){
    bool keep = (cnt >= nr) && (m[b*NN + i] > 0.f);
    m[b*NN + i]    = keep ? 1.0f : 0.0f;
    gate[b*NN + i] = keep ? tanhf(y[b*NN + i]) : 0.0f;
  }
  if (xx == 0 && tid == 0) ncur_out[b] = n - nr;
}

// ---------------- degree from new mask -> D, dg = D*gate ----------------
// R23: idx walk vectorized to short4 (same position->s0..s3 mapping => bit-exact)
__global__ void k_deg(const short* __restrict__ idx, const int* __restrict__ cnt,
                      const float* __restrict__ m, const float* __restrict__ gate,
                      float* __restrict__ D, float* __restrict__ dg){
  __shared__ float ml[NN];
  int blk = blockIdx.x, tid = threadIdx.x;   // grid 128, block = 256
  int r8 = blk & 7, t = blk >> 3;            // t 0..15
  int b = r8 + 8*(t >> 2), xx = t & 3;
  for (int i = tid; i < NN; i += 256) ml[i] = m[b*NN + i];
  __syncthreads();
  int j = xx*250 + tid;
  if (tid < 250){
    const short* r = idx + ((size_t)b*NN + j)*CAP;
    int n = cnt[b*NN + j];
    float s0=0.f, s1=0.f, s2=0.f, s3=0.f;
    int k = 0;
    for (; k+4 <= n; k += 4){
      short4 rv = *(const short4*)(r + k);   // 8B vector load (256B-aligned rows)
      s0 += ml[rv.x]; s1 += ml[rv.y]; s2 += ml[rv.z]; s3 += ml[rv.w];
    }
    for (; k < n; k++) s0 += ml[r[k]];
    float Dv = 1.0f / sqrtf(((s0+s1)+(s2+s3)) + 1.0f + 1e-5f);
    D[b*NN + j]  = Dv;
    dg[b*NN + j] = Dv * gate[b*NN + j];
  }
}

// ---------------- partial global max pool (masked rows skipped; relu => max>=0) ----------------
__global__ void k_fmax(const float* __restrict__ H, const float* __restrict__ m,
                       float* __restrict__ part){
  int blk = blockIdx.x, c = threadIdx.x;     // grid 256, block = 128
  int r8 = blk & 7, t = blk >> 3;            // t 0..31
  int b = r8 + 8*(t >> 3), sx = t & 7;
  float mx = 0.f;
  int i0 = sx*125;
  for (int i = i0; i < i0+125; i++){
    if (m[b*NN + i] != 0.f)
      mx = fmaxf(mx, H[((size_t)b*NN + i)*CC + c]);
  }
  part[((size_t)b*8 + sx)*CC + c] = mx;
}

// ---------------- combine partial maxima + FC ----------------
__global__ void k_fc(const float* __restrict__ part, const float* __restrict__ Wfc,
                     const float* __restrict__ bfc, float* __restrict__ out){
  __shared__ float g[FF];
  int b = blockIdx.x, tid = threadIdx.x;   // block = 128
  float mx = 0.f;
  #pragma unroll
  for (int s = 0; s < 8; s++) mx = fmaxf(mx, part[((size_t)b*8 + s)*CC + tid]);
  g[tid] = mx;
  __syncthreads();
  if (tid < OO){
    float acc = bfc[tid];
    for (int c = 0; c < FF; c++) acc += g[c]*Wfc[tid*FF + c];
    out[b*OO + tid] = acc;
  }
}

extern "C" void kernel_launch(void* const* d_in, const int* in_sizes, int n_in,
                              void* d_out, int out_size, void* d_ws, size_t ws_size,
                              hipStream_t stream) {
  const float* x    = (const float*)d_in[0];
  const float* A    = (const float*)d_in[1];
  const float* mask = (const float*)d_in[2];
  const int*   Nn   = (const int*)  d_in[3];
  const float* W0   = (const float*)d_in[4];
  const float* b0   = (const float*)d_in[5];
  const float* W1   = (const float*)d_in[6];
  const float* b1   = (const float*)d_in[7];
  const float* W2   = (const float*)d_in[8];
  const float* b2   = (const float*)d_in[9];
  const float* p0   = (const float*)d_in[10];
  const float* p1   = (const float*)d_in[11];
  const float* Wfc  = (const float*)d_in[12];
  const float* bfc  = (const float*)d_in[13];
  float* out = (float*)d_out;

  // workspace carve (~42 MB)
  char* w = (char*)d_ws;
  float* H   = (float*)w; w += (size_t)BB*NN*CC*4;      // 16.38 MB (ping)
  float* H2  = (float*)w; w += (size_t)BB*NN*CC*4;      // 16.38 MB (pong)
  short* idx = (short*)w; w += (size_t)BB*NN*CAP*2;     // 8.19 MB
  float* Wt  = (float*)w; w += (size_t)3*FF*CC*4;       // 192 KB
  float* part= (float*)w; w += (size_t)8*BB*CC*4;       // 131 KB
  int*   cnt = (int*)w;   w += (size_t)BB*NN*4;
  float* D   = (float*)w; w += (size_t)BB*NN*4;
  float* m   = (float*)w; w += (size_t)BB*NN*4;
  float* ysc = (float*)w; w += (size_t)BB*NN*4;
  float* gate= (float*)w; w += (size_t)BB*NN*4;
  float* dg  = (float*)w; w += (size_t)BB*NN*4;
  int*   ncur= (int*)w;   w += 3*BB*sizeof(int);        // ping-pong slots
  float* pn  = (float*)w; w += 64;

  // CSR + all pre-work in one dispatch
  k_csr<<<32032, 64, 0, stream>>>(A, mask, Nn, p0, p1, W0, W1, W2,
                                  idx, cnt, D, dg, m, gate, ncur, pn, Wt);

  // ---- stage 1: x -> H ----
  k_agglin<<<800, 512, 0, stream>>>(idx, cnt, D, dg, m, gate, x,
                                    Wt + 0*FF*CC, b0, H);
  k_score<<<32000, 64, 0, stream>>>(H, p0, pn + 0, ysc);
  k_pool<<<128, 256, 0, stream>>>(ysc, m, ncur + 0*BB, ncur + 1*BB, gate);
  k_deg<<<128, 256, 0, stream>>>(idx, cnt, m, gate, D, dg);

  // ---- stage 2: H -> H2 ----
  k_agglin<<<800, 512, 0, stream>>>(idx, cnt, D, dg, m, gate, H,
                                    Wt + 1*FF*CC, b1, H2);
  k_score<<<32000, 64, 0, stream>>>(H2, p1, pn + 1, ysc);
  k_pool<<<128, 256, 0, stream>>>(ysc, m, ncur + 1*BB, ncur + 2*BB, gate);
  k_deg<<<128, 256, 0, stream>>>(idx, cnt, m, gate, D, dg);

  // ---- stage 3: H2 -> H ----
  k_agglin<<<800, 512, 0, stream>>>(idx, cnt, D, dg, m, gate, H2,
                                    Wt + 2*FF*CC, b2, H);

  // ---- global max pool + FC ----
  k_fmax<<<256, 128, 0, stream>>>(H, m, part);
  k_fc<<<BB, 128, 0, stream>>>(part, Wfc, bfc, out);
}

// Round 14
// 442.718 us; speedup vs baseline: 6.8352x; 1.0448x over previous
//
#include <hip/hip_runtime.h>
#include <math.h>

#define BB 32
#define NN 1000
#define CC 128
#define FF 128
#define OO 64
#define CAP 128
#define NB 40

// exact replica of JAX's np.float32(1.0 - 0.8) = 0.20000000298023224f
#define RMC ((float)(1.0 - 0.8))

// ======== R24: TERMINAL REVERT TO R7/R17 (session best, 443.06 us) ========
// R13's 16-deep gather regressed +19us (pad-to-32 adds ~30% dummy loads for
// low-degree rows). 14-round ledger closes every mechanism class: sync (R1),
// boundary-fusion (R2/R6: starvation), XCD pinning (R4), T-roundtrip (R5),
// TLP (R7), L2 prewarm (R9/R10: vmcnt FIFO makes it impossible), cooperative
// mono (R11: grid.sync flushes L2, 6.8x), LDS chunking (R12: metadata x8),
// deeper MLP (R13: pad work). Only real win ever: gather 4->8 in-flight (R4,
// -15us). Structural floor: ~320us kernel floors (aggregation bound by
// post-boundary random-512B L3 service, parallelism/prefetch-insensitive)
// + ~120us dispatch boundaries (irreducible without starvation/flush).

// ---- CSR build + stage-1 D/dg + fused pre-work (blocks with i==NN) ----
__global__ void k_csr(const float* __restrict__ A, const float* __restrict__ mask,
                      const int* __restrict__ Nn,
                      const float* __restrict__ p0, const float* __restrict__ p1,
                      const float* __restrict__ W0, const float* __restrict__ W1,
                      const float* __restrict__ W2,
                      short* __restrict__ idx, int* __restrict__ cnt,
                      float* __restrict__ D, float* __restrict__ dg,
                      float* __restrict__ m, float* __restrict__ gate,
                      int* __restrict__ ncur0, float* __restrict__ pn,
                      float* __restrict__ Wt){
  int blk = blockIdx.x, lane = threadIdx.x;   // grid 32032, block = 64 (one wave)
  int r8 = blk & 7, t = blk >> 3;             // t 0..4003
  int b = r8 + 8*(t/1001), i = t % 1001;      // XCD-spread decode
  if (i == NN){                            // ---- 32 pre-work blocks ----
    for (int j = lane; j < NN; j += 64){
      float v = mask[b*NN + j]; m[b*NN + j] = v; gate[b*NN + j] = v;
    }
    if (lane == 0) ncur0[b] = Nn[b];
    if (b == 0 && lane == 1){ float s=0.f; for(int c=0;c<FF;c++) s += p0[c]*p0[c]; pn[0] = sqrtf(s); }
    if (b == 1 && lane == 1){ float s=0.f; for(int c=0;c<FF;c++) s += p1[c]*p1[c]; pn[1] = sqrtf(s); }
    // Wt[s][c][f] = W[s][f][c]; 3*FF*CC = 49152 elems, 1536 per block
    for (int e = b*1536 + lane; e < (b+1)*1536; e += 64){
      int s = e / (FF*CC), rem = e % (FF*CC);
      int c = rem >> 7, f = rem & 127;
      const float* W = (s == 0) ? W0 : (s == 1) ? W1 : W2;
      Wt[(size_t)s*FF*CC + rem] = W[f*CC + c];
    }
    return;
  }
  if (mask[b*NN + i] == 0.f){              // A row is all-zero (A pre-masked)
    if (lane == 0){
      cnt[b*NN + i] = 0;
      D[b*NN + i]  = 1.0f / sqrtf(1.0f + 1e-5f);
      dg[b*NN + i] = 0.f;
    }
    return;
  }
  const float4* row = (const float4*)(A + ((size_t)b*NN + i)*NN);
  short* out = idx + ((size_t)b*NN + i)*CAP;
  int count = 0;
  for (int base = 0; base < 250; base += 64){               // 1000 = 250 float4
    int q = base + lane;
    float4 v;
    if (q < 250) v = row[q]; else { v.x=v.y=v.z=v.w=0.f; }
    int lc = (v.x!=0.f) + (v.y!=0.f) + (v.z!=0.f) + (v.w!=0.f);
    int pre = lc;
    #pragma unroll
    for (int off = 1; off < 64; off <<= 1){
      int t2 = __shfl_up(pre, off);
      if (lane >= off) pre += t2;
    }
    int tot = __shfl(pre, 63);
    pre -= lc;                                              // exclusive prefix
    int slot = count + pre;
    int j = q*4;
    if (v.x!=0.f && slot < CAP) out[slot++] = (short)j;
    if (v.y!=0.f && slot < CAP) out[slot++] = (short)(j+1);
    if (v.z!=0.f && slot < CAP) out[slot++] = (short)(j+2);
    if (v.w!=0.f && slot < CAP) out[slot++] = (short)(j+3);
    count += tot;
  }
  if (lane == 0){
    int cn = (count < CAP) ? count : CAP;
    cnt[b*NN + i] = cn;
    float Dv = 1.0f / sqrtf((float)cn + 1.0f + 1e-5f);
    D[b*NN + i]  = Dv;
    dg[b*NN + i] = Dv;                   // mask_i == 1 here
  }
}

// ---- FUSED: T-tile into LDS (phase 1, 8 waves x 5 rows) + frozen GEMM ----
__global__ void k_agglin(const short* __restrict__ idx, const int* __restrict__ cnt,
                         const float* __restrict__ D, const float* __restrict__ dg,
                         const float* __restrict__ m, const float* __restrict__ gate,
                         const float* __restrict__ h,
                         const float* __restrict__ Wt,   // [cc][f] transposed
                         const float* __restrict__ bias, float* __restrict__ Hout){
  __shared__ float t[NB][CC];              // 20.5 KB (the old T staging buffer)
  __shared__ int   nb[8][CAP];             // per-wave gather scratch (4 KB)
  __shared__ float dn[8][CAP];             // (4 KB)
  int blk = blockIdx.x, tid = threadIdx.x; // grid 800, block = 512 (8 waves)
  int r8 = blk & 7, tq = blk >> 3;         // tq 0..99
  int b = r8 + 8*(tq/25);
  int i0 = (tq % 25) * NB;
  int w = tid >> 6, lane = tid & 63;
  int g = lane >> 5, l32 = lane & 31;
  const float* hb = h + (size_t)b*NN*CC;
  int*   nbw = nb[w];
  float* dnw = dn[w];
  // ================= phase 1: aggregate 40 rows into t (5 rows/wave) ====
  for (int q = 0; q < 5; q++){             // wave w owns local rows w, w+8, ... w+32
    int lr = q*8 + w;
    int i  = i0 + lr;
    if (m[b*NN + i] == 0.f){               // masked target: T row is zero
      if (g == 0){ float4 z = {0.f,0.f,0.f,0.f}; *(float4*)&t[lr][l32<<2] = z; }
      continue;                            // wave-uniform
    }
    int n = cnt[b*NN + i];
    const short* r = idx + ((size_t)b*NN + i)*CAP;
    // --- wave-level order-preserving compaction: keep edges with dn != 0 ---
    int j0 = 0; float d0 = 0.f; bool k0 = false;
    if (lane < n){ j0 = (int)r[lane]; d0 = dg[b*NN + j0]; k0 = (d0 != 0.f); }
    unsigned long long bal = __ballot(k0);
    int pre = __popcll(bal & ((1ull << lane) - 1ull));
    if (k0){ nbw[pre] = j0*CC; dnw[pre] = d0; }
    int nlive = __popcll(bal);
    if (n > 64){                           // wave-uniform branch
      int e = lane + 64; int j1 = 0; float d1 = 0.f; bool k1 = false;
      if (e < n){ j1 = (int)r[e]; d1 = dg[b*NN + j1]; k1 = (d1 != 0.f); }
      unsigned long long bal1 = __ballot(k1);
      int pre1 = __popcll(bal1 & ((1ull << lane) - 1ull));
      if (k1){ nbw[nlive + pre1] = j1*CC; dnw[nlive + pre1] = d1; }
      nlive += __popcll(bal1);
    }
    int np = (nlive + 15) & ~15;           // pad to 16 (CAP=128 safe)
    if (lane < np - nlive){ nbw[nlive + lane] = 0; dnw[nlive + lane] = 0.f; }
    __builtin_amdgcn_wave_barrier();       // fence: LDS writes before reads
    // --- branch-free float4 gather, 8 loads/lane in flight (R5 order) ---
    float4 a0 = {0.f,0.f,0.f,0.f}, a1 = a0, a2 = a0, a3 = a0;
    for (int k = 0; k < np; k += 16){
      int e = k + g;
      float4 v0 = *(const float4*)(hb + nbw[e   ] + (l32<<2));
      float4 v1 = *(const float4*)(hb + nbw[e+ 2] + (l32<<2));
      float4 v2 = *(const float4*)(hb + nbw[e+ 4] + (l32<<2));
      float4 v3 = *(const float4*)(hb + nbw[e+ 6] + (l32<<2));
      float4 v4 = *(const float4*)(hb + nbw[e+ 8] + (l32<<2));
      float4 v5 = *(const float4*)(hb + nbw[e+10] + (l32<<2));
      float4 v6 = *(const float4*)(hb + nbw[e+12] + (l32<<2));
      float4 v7 = *(const float4*)(hb + nbw[e+14] + (l32<<2));
      float e0 = dnw[e], e1 = dnw[e+2], e2 = dnw[e+4], e3 = dnw[e+6];
      float e4 = dnw[e+8], e5 = dnw[e+10], e6 = dnw[e+12], e7 = dnw[e+14];
      a0.x += e0*v0.x; a0.y += e0*v0.y; a0.z += e0*v0.z; a0.w += e0*v0.w;
      a1.x += e1*v1.x; a1.y += e1*v1.y; a1.z += e1*v1.z; a1.w += e1*v1.w;
      a2.x += e2*v2.x; a2.y += e2*v2.y; a2.z += e2*v2.z; a2.w += e2*v2.w;
      a3.x += e3*v3.x; a3.y += e3*v3.y; a3.z += e3*v3.z; a3.w += e3*v3.w;
      a0.x += e4*v4.x; a0.y += e4*v4.y; a0.z += e4*v4.z; a0.w += e4*v4.w;
      a1.x += e5*v5.x; a1.y += e5*v5.y; a1.z += e5*v5.z; a1.w += e5*v5.w;
      a2.x += e6*v6.x; a2.y += e6*v6.y; a2.z += e6*v6.z; a2.w += e6*v6.w;
      a3.x += e7*v7.x; a3.y += e7*v7.y; a3.z += e7*v7.z; a3.w += e7*v7.w;
    }
    float4 Y;
    Y.x = (a0.x + a1.x) + (a2.x + a3.x);
    Y.y = (a0.y + a1.y) + (a2.y + a3.y);
    Y.z = (a0.z + a1.z) + (a2.z + a3.z);
    Y.w = (a0.w + a1.w) + (a2.w + a3.w);
    Y.x += __shfl_xor(Y.x, 32);            // combine the two 32-lane groups
    Y.y += __shfl_xor(Y.y, 32);
    Y.z += __shfl_xor(Y.z, 32);
    Y.w += __shfl_xor(Y.w, 32);
    float Di = D[b*NN + i];
    float gi = gate[b*NN + i];
    if (g == 0){
      float4 hv = *(const float4*)(hb + (size_t)i*CC + (l32<<2));
      float4 o;
      o.x = Di*Y.x + Di*Di*(gi*hv.x);
      o.y = Di*Y.y + Di*Di*(gi*hv.y);
      o.z = Di*Y.z + Di*Di*(gi*hv.z);
      o.w = Di*Y.w + Di*Di*(gi*hv.w);
      *(float4*)&t[lr][l32<<2] = o;
    }
  }
  __syncthreads();
  // ================= phase 2: FROZEN R3 GEMM body (verbatim, waves 0-3) =====
  if (tid < 256){
    int fg = tid & 31;                     // 4 consecutive f per thread
    int nr = tid >> 5;                     // 0..7 node-row
    float acc[5][4];
    float4 bi = ((const float4*)bias)[fg];
    #pragma unroll
    for (int n5 = 0; n5 < 5; n5++){
      acc[n5][0]=bi.x; acc[n5][1]=bi.y; acc[n5][2]=bi.z; acc[n5][3]=bi.w;
    }
    for (int c4 = 0; c4 < 32; c4++){
      float4 tv[5];
      #pragma unroll
      for (int n5 = 0; n5 < 5; n5++)
        tv[n5] = *((const float4*)&t[nr + n5*8][c4*4]);
      #pragma unroll
      for (int k = 0; k < 4; k++){
        float4 wv = ((const float4*)Wt)[(size_t)(c4*4 + k)*32 + fg];
        #pragma unroll
        for (int n5 = 0; n5 < 5; n5++){
          float tvv = (k==0) ? tv[n5].x : (k==1) ? tv[n5].y : (k==2) ? tv[n5].z : tv[n5].w;
          acc[n5][0] += tvv*wv.x; acc[n5][1] += tvv*wv.y;
          acc[n5][2] += tvv*wv.z; acc[n5][3] += tvv*wv.w;
        }
      }
    }
    #pragma unroll
    for (int n5 = 0; n5 < 5; n5++){
      int i = i0 + nr + n5*8;
      float mi = m[b*NN + i];
      float4 o4;
      o4.x = fmaxf(acc[n5][0], 0.f)*mi;
      o4.y = fmaxf(acc[n5][1], 0.f)*mi;
      o4.z = fmaxf(acc[n5][2], 0.f)*mi;
      o4.w = fmaxf(acc[n5][3], 0.f)*mi;
      ((float4*)&Hout[((size_t)b*NN + i)*CC])[fg] = o4;
    }
  }
}

// ---------------- pool scores y_i = (H_i . p) / |p| ----------------
__global__ void k_score(const float* __restrict__ H, const float* __restrict__ p,
                        const float* __restrict__ pn, float* __restrict__ y){
  int blk = blockIdx.x, lane = threadIdx.x;  // grid 32000, block = 64
  int r8 = blk & 7, t = blk >> 3;            // t 0..3999
  int b = r8 + 8*(t/1000), i = t % 1000;
  const float* hrow = H + ((size_t)b*NN + i)*CC;
  float s = hrow[lane]*p[lane] + hrow[lane+64]*p[lane+64];
  for (int off = 32; off > 0; off >>= 1) s += __shfl_down(s, off);
  if (lane == 0) y[b*NN + i] = s / pn[0];
}

// ---------------- top-k pool: 1 node/thread, float4 LDS scan, ping-pong ncur ----------------
__global__ void k_pool(const float* __restrict__ y, float* __restrict__ m,
                       const int* __restrict__ ncur_in, int* __restrict__ ncur_out,
                       float* __restrict__ gate){
  __shared__ float yk[NN];
  int blk = blockIdx.x, tid = threadIdx.x;   // grid 128, block = 256
  int r8 = blk & 7, t = blk >> 3;            // t 0..15
  int b = r8 + 8*(t >> 2), xx = t & 3;
  int i = xx*256 + tid;
  for (int j = tid; j < NN; j += 256)
    yk[j] = (m[b*NN + j] > 0.f) ? y[b*NN + j] : INFINITY;
  __syncthreads();
  int n = ncur_in[b];
  int nr = (int)((float)n * RMC);          // exact JAX semantics (f32 mult, trunc)
  float myv = (i < NN) ? yk[i] : INFINITY;
  int cnt = 0;
  const float4* yk4 = (const float4*)yk;   // broadcast reads: conflict-free
  #pragma unroll 5
  for (int q = 0; q < 250; q++){
    float4 v = yk4[q];
    int j0 = q*4;
    cnt += (int)((v.x < myv) || (v.x == myv && j0     < i));
    cnt += (int)((v.y < myv) || (v.y == myv && j0 + 1 < i));
    cnt += (int)((v.z < myv) || (v.z == myv && j0 + 2 < i));
    cnt += (int)((v.w < myv) || (v.w == myv && j0 + 3 < i));
  }
  if (i < NN){
    bool keep = (cnt >= nr) && (m[b*NN + i] > 0.f);
    m[b*NN + i]    = keep ? 1.0f : 0.0f;
    gate[b*NN + i] = keep ? tanhf(y[b*NN + i]) : 0.0f;
  }
  if (xx == 0 && tid == 0) ncur_out[b] = n - nr;
}

// ---------------- degree from new mask -> D, dg = D*gate ----------------
__global__ void k_deg(const short* __restrict__ idx, const int* __restrict__ cnt,
                      const float* __restrict__ m, const float* __restrict__ gate,
                      float* __restrict__ D, float* __restrict__ dg){
  __shared__ float ml[NN];
  int blk = blockIdx.x, tid = threadIdx.x;   // grid 128, block = 256
  int r8 = blk & 7, t = blk >> 3;            // t 0..15
  int b = r8 + 8*(t >> 2), xx = t & 3;
  for (int i = tid; i < NN; i += 256) ml[i] = m[b*NN + i];
  __syncthreads();
  int j = xx*250 + tid;
  if (tid < 250){
    const short* r = idx + ((size_t)b*NN + j)*CAP;
    int n = cnt[b*NN + j];
    float s0=0.f, s1=0.f, s2=0.f, s3=0.f;
    int k = 0;
    for (; k+4 <= n; k += 4){
      s0 += ml[r[k]]; s1 += ml[r[k+1]]; s2 += ml[r[k+2]]; s3 += ml[r[k+3]];
    }
    for (; k < n; k++) s0 += ml[r[k]];
    float Dv = 1.0f / sqrtf(((s0+s1)+(s2+s3)) + 1.0f + 1e-5f);
    D[b*NN + j]  = Dv;
    dg[b*NN + j] = Dv * gate[b*NN + j];
  }
}

// ---------------- partial global max pool (masked rows skipped; relu => max>=0) ----------------
__global__ void k_fmax(const float* __restrict__ H, const float* __restrict__ m,
                       float* __restrict__ part){
  int blk = blockIdx.x, c = threadIdx.x;     // grid 256, block = 128
  int r8 = blk & 7, t = blk >> 3;            // t 0..31
  int b = r8 + 8*(t >> 3), sx = t & 7;
  float mx = 0.f;
  int i0 = sx*125;
  for (int i = i0; i < i0+125; i++){
    if (m[b*NN + i] != 0.f)
      mx = fmaxf(mx, H[((size_t)b*NN + i)*CC + c]);
  }
  part[((size_t)b*8 + sx)*CC + c] = mx;
}

// ---------------- combine partial maxima + FC ----------------
__global__ void k_fc(const float* __restrict__ part, const float* __restrict__ Wfc,
                     const float* __restrict__ bfc, float* __restrict__ out){
  __shared__ float g[FF];
  int b = blockIdx.x, tid = threadIdx.x;   // block = 128
  float mx = 0.f;
  #pragma unroll
  for (int s = 0; s < 8; s++) mx = fmaxf(mx, part[((size_t)b*8 + s)*CC + tid]);
  g[tid] = mx;
  __syncthreads();
  if (tid < OO){
    float acc = bfc[tid];
    for (int c = 0; c < FF; c++) acc += g[c]*Wfc[tid*FF + c];
    out[b*OO + tid] = acc;
  }
}

extern "C" void kernel_launch(void* const* d_in, const int* in_sizes, int n_in,
                              void* d_out, int out_size, void* d_ws, size_t ws_size,
                              hipStream_t stream) {
  const float* x    = (const float*)d_in[0];
  const float* A    = (const float*)d_in[1];
  const float* mask = (const float*)d_in[2];
  const int*   Nn   = (const int*)  d_in[3];
  const float* W0   = (const float*)d_in[4];
  const float* b0   = (const float*)d_in[5];
  const float* W1   = (const float*)d_in[6];
  const float* b1   = (const float*)d_in[7];
  const float* W2   = (const float*)d_in[8];
  const float* b2   = (const float*)d_in[9];
  const float* p0   = (const float*)d_in[10];
  const float* p1   = (const float*)d_in[11];
  const float* Wfc  = (const float*)d_in[12];
  const float* bfc  = (const float*)d_in[13];
  float* out = (float*)d_out;

  // workspace carve (~42 MB)
  char* w = (char*)d_ws;
  float* H   = (float*)w; w += (size_t)BB*NN*CC*4;      // 16.38 MB (ping)
  float* H2  = (float*)w; w += (size_t)BB*NN*CC*4;      // 16.38 MB (pong)
  short* idx = (short*)w; w += (size_t)BB*NN*CAP*2;     // 8.19 MB
  float* Wt  = (float*)w; w += (size_t)3*FF*CC*4;       // 192 KB
  float* part= (float*)w; w += (size_t)8*BB*CC*4;       // 131 KB
  int*   cnt = (int*)w;   w += (size_t)BB*NN*4;
  float* D   = (float*)w; w += (size_t)BB*NN*4;
  float* m   = (float*)w; w += (size_t)BB*NN*4;
  float* ysc = (float*)w; w += (size_t)BB*NN*4;
  float* gate= (float*)w; w += (size_t)BB*NN*4;
  float* dg  = (float*)w; w += (size_t)BB*NN*4;
  int*   ncur= (int*)w;   w += 3*BB*sizeof(int);        // ping-pong slots
  float* pn  = (float*)w; w += 64;

  // CSR + all pre-work in one dispatch
  k_csr<<<32032, 64, 0, stream>>>(A, mask, Nn, p0, p1, W0, W1, W2,
                                  idx, cnt, D, dg, m, gate, ncur, pn, Wt);

  // ---- stage 1: x -> H ----
  k_agglin<<<800, 512, 0, stream>>>(idx, cnt, D, dg, m, gate, x,
                                    Wt + 0*FF*CC, b0, H);
  k_score<<<32000, 64, 0, stream>>>(H, p0, pn + 0, ysc);
  k_pool<<<128, 256, 0, stream>>>(ysc, m, ncur + 0*BB, ncur + 1*BB, gate);
  k_deg<<<128, 256, 0, stream>>>(idx, cnt, m, gate, D, dg);

  // ---- stage 2: H -> H2 ----
  k_agglin<<<800, 512, 0, stream>>>(idx, cnt, D, dg, m, gate, H,
                                    Wt + 1*FF*CC, b1, H2);
  k_score<<<32000, 64, 0, stream>>>(H2, p1, pn + 1, ysc);
  k_pool<<<128, 256, 0, stream>>>(ysc, m, ncur + 1*BB, ncur + 2*BB, gate);
  k_deg<<<128, 256, 0, stream>>>(idx, cnt, m, gate, D, dg);

  // ---- stage 3: H2 -> H ----
  k_agglin<<<800, 512, 0, stream>>>(idx, cnt, D, dg, m, gate, H2,
                                    Wt + 2*FF*CC, b2, H);

  // ---- global max pool + FC ----
  k_fmax<<<256, 128, 0, stream>>>(H, m, part);
  k_fc<<<BB, 128, 0, stream>>>(part, Wfc, bfc, out);
}